// Round 3
// baseline (452.741 us; speedup 1.0000x reference)
//
#include <hip/hip_runtime.h>
#include <stdint.h>

// Round 10: attack k_accum read amplification + partial round-trip.
//  Round-9 post-mortem: 442us = 160us harness poison + ~282us kernels. Model
//  says k_accum fetches 225 MB for 67 MB of payload (13.7-event segments =
//  55 B touch ~1.43 x 128 B lines, 1.23M segments) and the partial buffer
//  round-trips 157 MB.
//  Fixes:
//   CHUNK 2048->4096 (EVT=16, B1=4096): segments halve, span 110 B ->
//     payload fetch ~145 MB. k_bin scan work halves. pfx halves.
//   SLICES 16->8: partial traffic 157->78 MB. Mapping g=bid>>3, s=bid&7 puts
//     slice s of every group on XCD s (round-robin bid%8) -> boundary lines
//     of adjacent groups (g,s)/(g+1,s) share one XCD L2.
//   k_transpose dropped: k_bin writes pfxT [NG][B1] directly (150 scattered
//     u16 stores/block, L2 write-combines; pfxT = 1.2 MB).
//
// payload word: tok<<24 | (bucket&15)<<20 | q20(wt).  hist key = w>>20.
// ws: payload u32*n | pfxT u16[NG][B1] | partial u64[SLICES][NG][4096]

#define TPB 256
#define B1 4096
#define CHUNK 4096                 // B1*CHUNK = 2^24 = n
#define EVT (CHUNK / TPB)          // 16 events per thread
#define NBUCKET 2400
#define SCAN_PER 10                // ceil(NBUCKET/TPB)
#define GACC 16                    // buckets per group
#define NG (NBUCKET / GACC)        // 150 groups
#define SLICES 8
#define RPS (B1 / SLICES)          // 512 rows per slice
#define HCELLS (GACC * 256)        // 4096 cells per group
#define ATPB 512                   // k_accum block size (8 waves)
#define OUT_CH_STRIDE 76800        // 256*300
#define OUT_DP_STRIDE 153600       // 2*256*300

__device__ __forceinline__ void classify_full(const float4 e, const float t0,
                                              const float d_wt, const float d_dt,
                                              int& bucket, int& tok, float& wt) {
    const float c1 = (float)(319.0 / 20.0 + 1e-4);   // W/PW + B
    const float c2 = (float)(239.0 / 15.0 + 1e-4);   // H/PH + B
    const int pos = (int)(floorf(e.y / c1) + floorf(e.z / c2) * 20.0f);
    tok = (int)(floorf(fmodf(e.y, c1)) + floorf(fmodf(e.z, c2)) * 16.0f);
    const int dt = (int)floorf(4.0f * (e.x - t0) / d_dt);
    const int p  = (int)e.w;
    bucket = (dt * 2 + p) * 300 + pos;
    wt = (e.x - t0) / d_wt;
}

__global__ __launch_bounds__(TPB) void k_bin(const float4* __restrict__ x,
                                             uint32_t* __restrict__ payload,
                                             uint16_t* __restrict__ pfxT,
                                             int n) {
    __shared__ uint32_t stage[CHUNK];     // 16 KB
    __shared__ uint32_t cnt[NBUCKET];     // 9.6 KB: counts, then prefixes
    __shared__ uint32_t wsum[TPB / 64];

    for (int i = threadIdx.x; i < NBUCKET; i += TPB) cnt[i] = 0;
    __syncthreads();

    const float* xf = (const float*)x;
    const float t0 = xf[0];
    const float tlast = xf[(size_t)(n - 1) * 4];
    const float d_wt = tlast - t0 + 1e-4f;
    const float d_dt = tlast - t0 + 1.0f;

    const int beg = blockIdx.x * CHUNK;
    const bool full = (beg + CHUNK <= n);

    // phase 1: classify once; atomicAdd returns within-bucket rank (stash it)
    uint32_t pk[EVT];
    uint32_t bk[EVT];
    if (full) {
        #pragma unroll
        for (int k = 0; k < EVT; ++k) {
            float4 e = x[beg + threadIdx.x + k * TPB];
            int bucket, tok; float wt;
            classify_full(e, t0, d_wt, d_dt, bucket, tok, wt);
            uint32_t q = (uint32_t)(wt * 1048576.0f);          // q20
            q = q > 1048575u ? 1048575u : q;
            pk[k] = ((uint32_t)tok << 24) | ((uint32_t)(bucket & 15) << 20) | q;
            uint32_t rank = atomicAdd(&cnt[bucket], 1u);
            bk[k] = (uint32_t)bucket | (rank << 12);           // bucket:12 rank:12
        }
    } else {
        #pragma unroll
        for (int k = 0; k < EVT; ++k) {
            const int i = beg + threadIdx.x + k * TPB;
            if (i < n) {
                float4 e = x[i];
                int bucket, tok; float wt;
                classify_full(e, t0, d_wt, d_dt, bucket, tok, wt);
                uint32_t q = (uint32_t)(wt * 1048576.0f);
                q = q > 1048575u ? 1048575u : q;
                pk[k] = ((uint32_t)tok << 24) | ((uint32_t)(bucket & 15) << 20) | q;
                uint32_t rank = atomicAdd(&cnt[bucket], 1u);
                bk[k] = (uint32_t)bucket | (rank << 12);
            } else {
                bk[k] = 0xFFFFFFFFu;
            }
        }
    }
    __syncthreads();

    // phase 2: block-local exclusive scan of NBUCKET counts
    uint32_t v[SCAN_PER];
    uint32_t sum = 0;
    const int base_i = threadIdx.x * SCAN_PER;
    #pragma unroll
    for (int j = 0; j < SCAN_PER; ++j) {
        int idx = base_i + j;
        uint32_t c = (idx < NBUCKET) ? cnt[idx] : 0u;
        v[j] = sum;
        sum += c;
    }
    uint32_t inc = sum;
    #pragma unroll
    for (int off = 1; off < 64; off <<= 1) {
        uint32_t u = __shfl_up(inc, off, 64);
        if ((threadIdx.x & 63) >= off) inc += u;
    }
    const int wid = threadIdx.x >> 6, lid = threadIdx.x & 63;
    if (lid == 63) wsum[wid] = inc;
    __syncthreads();
    uint32_t woff = 0;
    for (int w = 0; w < wid; ++w) woff += wsum[w];
    const uint32_t excl = woff + inc - sum;

    #pragma unroll
    for (int j = 0; j < SCAN_PER; ++j) {
        int idx = base_i + j;
        if (idx < NBUCKET) {
            uint32_t p = excl + v[j];
            cnt[idx] = p;                        // exclusive prefix (read-only below)
            if ((idx & 15) == 0)                 // group start, direct-transposed
                pfxT[(size_t)(idx >> 4) * B1 + blockIdx.x] = (uint16_t)p;
        }
    }
    __syncthreads();

    // phase 3: plain indexed store (rank came from the phase-1 atomic)
    if (full) {
        #pragma unroll
        for (int k = 0; k < EVT; ++k)
            stage[cnt[bk[k] & 0xFFFu] + (bk[k] >> 12)] = pk[k];
    } else {
        #pragma unroll
        for (int k = 0; k < EVT; ++k)
            if (bk[k] != 0xFFFFFFFFu)
                stage[cnt[bk[k] & 0xFFFu] + (bk[k] >> 12)] = pk[k];
    }
    __syncthreads();

    // phase 4: coalesced LDS -> global writeout
    const int end = min(beg + CHUNK, n);
    const int cntE = end > beg ? end - beg : 0;
    uint32_t* pbase = payload + (size_t)blockIdx.x * CHUNK;
    const int n4 = cntE >> 2;
    const uint4* s4 = (const uint4*)stage;
    uint4* g4 = (uint4*)pbase;
    for (int i = threadIdx.x; i < n4; i += TPB) g4[i] = s4[i];
    for (int i = (n4 << 2) + threadIdx.x; i < cntE; i += TPB) pbase[i] = stage[i];
}

// One block per (group, row-slice): 150 x 8 = 1200 blocks, 32 KB LDS hist
// -> 4 blocks/CU, 32 waves/CU. g = bid>>3, s = bid&7 so XCD s (round-robin
// bid%8) owns slice s of ALL groups: adjacent groups' shared boundary lines
// stay in one XCD L2. Each wave owns 64 rows; 16-lane quarters stream each
// row's payload span (coalesced u32 runs).
__global__ __launch_bounds__(ATPB) void k_accum(const uint32_t* __restrict__ payload,
                                                const uint16_t* __restrict__ pfxT,
                                                unsigned long long* __restrict__ partial,
                                                int n) {
    const int g = blockIdx.x >> 3;
    const int s = blockIdx.x & 7;

    __shared__ unsigned long long hist[HCELLS];   // 32 KB: (tok*16+c) -> cnt<<40 | q20sum
    for (int i = threadIdx.x; i < HCELLS; i += ATPB) hist[i] = 0ULL;
    __syncthreads();

    const uint16_t* colb = pfxT + (size_t)g * B1;
    const bool last = (g == NG - 1);
    const uint16_t* cole = colb + B1;             // valid iff !last

    const int wid = threadIdx.x >> 6, lid = threadIdx.x & 63;
    const int r0 = s * RPS + wid * 64;            // 8 waves x 64 rows = 512 = RPS

    const int row = r0 + lid;
    uint32_t vb = colb[row];                      // coalesced u16 loads
    uint32_t ve;
    if (!last) {
        ve = cole[row];
    } else {
        int rc = n - row * CHUNK;
        ve = rc < 0 ? 0 : (rc > CHUNK ? CHUNK : rc);
    }

    const int q4 = lid >> 4;                      // quarter 0..3
    const int ql = lid & 15;
    for (int r = 0; r < 64; r += 4) {
        const int rr = r + q4;
        const uint32_t sb = __shfl(vb, rr, 64);
        const uint32_t se = __shfl(ve, rr, 64);
        const uint32_t* seg = payload + (size_t)(r0 + rr) * CHUNK;
        for (uint32_t j = sb + ql; j < se; j += 16) {
            const uint32_t w = seg[j];
            atomicAdd(&hist[w >> 20],
                      (1ULL << 40) | (unsigned long long)(w & 0xFFFFFu));
        }
    }
    __syncthreads();

    // coalesced partial writeout (every cell written -> no ws pre-zero)
    unsigned long long* pp = partial + ((size_t)s * NG + g) * HCELLS;
    for (int i = threadIdx.x; i < HCELLS; i += ATPB) pp[i] = hist[i];
}

// Sum 8 partials per cell; coalesced reads AND writes (consecutive cells ->
// consecutive pos because key = tok*16 + c). 614,400 cells, each out written
// exactly once -> no out memset.
__global__ __launch_bounds__(256) void k_out(const unsigned long long* __restrict__ partial,
                                             float* __restrict__ out) {
    const int i = blockIdx.x * 256 + threadIdx.x;   // cell id
    unsigned long long v = 0ULL;
    #pragma unroll
    for (int s = 0; s < SLICES; ++s)
        v += partial[(size_t)s * (NG * HCELLS) + i];
    const int g = i >> 12;
    const int idx = i & 4095;
    const int tok = idx >> 4;
    const int c = idx & 15;
    const int b = g * GACC + c;
    const int pos = b % 300;
    const int dp = b / 300;
    const float cntf = (float)(uint32_t)(v >> 40);
    const float wts  = (float)(v & ((1ULL << 40) - 1)) * (1.0f / 1048576.0f);
    const int base0 = dp * OUT_DP_STRIDE + tok * 300 + pos;
    out[base0] = cntf;                     // channel 0: count
    out[base0 + OUT_CH_STRIDE] = wts;      // channel 1: wt sum
}

// ---- fallback (ws too small / n out of range) ----
__global__ __launch_bounds__(TPB) void e2src_hist_atomic(const float4* __restrict__ x,
                                                         float* __restrict__ out, int n) {
    const float* xf = (const float*)x;
    const float t0 = xf[0];
    const float tlast = xf[(size_t)(n - 1) * 4];
    const float d_wt = tlast - t0 + 1e-4f;
    const float d_dt = tlast - t0 + 1.0f;
    int i = blockIdx.x * blockDim.x + threadIdx.x;
    const int stride = gridDim.x * blockDim.x;
    for (; i < n; i += stride) {
        float4 e = x[i];
        int bucket, tok; float wt;
        classify_full(e, t0, d_wt, d_dt, bucket, tok, wt);
        const int dp = bucket / 300, pos = bucket % 300;
        const int base = dp * OUT_DP_STRIDE + tok * 300 + pos;
        unsafeAtomicAdd(out + base, 1.0f);
        unsafeAtomicAdd(out + base + OUT_CH_STRIDE, wt);
    }
}

extern "C" void kernel_launch(void* const* d_in, const int* in_sizes, int n_in,
                              void* d_out, int out_size, void* d_ws, size_t ws_size,
                              hipStream_t stream) {
    const float* x = (const float*)d_in[0];
    float* out = (float*)d_out;
    const int n = in_sizes[0] / 4;

    const size_t payload_bytes = ((size_t)n * 4u + 7u) & ~(size_t)7u;
    const size_t pfx_bytes = (size_t)B1 * NG * 2u;                 // 1,228,800
    const size_t part_bytes = (size_t)SLICES * NG * HCELLS * 8u;   // 39,321,600
    const size_t need = payload_bytes + pfx_bytes + part_bytes;

    if (ws_size < need || n > B1 * CHUNK || n <= 0) {
        hipMemsetAsync(d_out, 0, (size_t)out_size * sizeof(float), stream);
        if (n > 0)
            hipLaunchKernelGGL(e2src_hist_atomic, dim3(8192), dim3(TPB), 0, stream,
                               (const float4*)x, out, n);
        return;
    }

    uint32_t* payload = (uint32_t*)d_ws;
    uint16_t* pfxT = (uint16_t*)((char*)d_ws + payload_bytes);
    unsigned long long* partial =
        (unsigned long long*)((char*)d_ws + payload_bytes + pfx_bytes);

    hipLaunchKernelGGL(k_bin, dim3(B1), dim3(TPB), 0, stream,
                       (const float4*)x, payload, pfxT, n);
    hipLaunchKernelGGL(k_accum, dim3(NG * SLICES), dim3(ATPB), 0, stream,
                       payload, pfxT, partial, n);
    hipLaunchKernelGGL(k_out, dim3((NG * HCELLS) / 256), dim3(256), 0, stream,
                       partial, out);
}

// Round 4
// 449.077 us; speedup vs baseline: 1.0082x; 1.0082x over previous
//
#include <hip/hip_runtime.h>
#include <stdint.h>

// Round 11: fix the round-10 regression — EVT must stay 8.
//  Round-10 post-mortem: predicted 330-350, got 452 (worse than r9's 442).
//  CHUNK 4096 @ TPB=256 meant EVT=16 -> 32 stash VGPRs -> scratch spill,
//  the EXACT failure rounds 5/6 documented (spill = 143-240 MB hidden
//  global traffic). The k_accum improvements (halved segments, halved
//  partial traffic) were real but masked by k_bin's spill.
//  Fix: TPB 256->512 with CHUNK=4096 -> EVT=8 again (16 stash VGPRs,
//  proven spill-free). LDS 25.7 KB -> wave-capped 4 blocks/CU (32 w/CU).
//  k_accum / k_out unchanged from round 10.
//
// payload word: tok<<24 | (bucket&15)<<20 | q20(wt).  hist key = w>>20.
// ws: payload u32*n | pfxT u16[NG][B1] | partial u64[SLICES][NG][4096]

#define TPB 512
#define B1 4096
#define CHUNK 4096                 // B1*CHUNK = 2^24 = n
#define EVT (CHUNK / TPB)          // 8 events per thread (spill-free stash)
#define NBUCKET 2400
#define SCAN_PER 5                 // ceil(NBUCKET/TPB)
#define GACC 16                    // buckets per group
#define NG (NBUCKET / GACC)        // 150 groups
#define SLICES 8
#define RPS (B1 / SLICES)          // 512 rows per slice
#define HCELLS (GACC * 256)        // 4096 cells per group
#define ATPB 512                   // k_accum block size (8 waves)
#define OUT_CH_STRIDE 76800        // 256*300
#define OUT_DP_STRIDE 153600       // 2*256*300

__device__ __forceinline__ void classify_full(const float4 e, const float t0,
                                              const float d_wt, const float d_dt,
                                              int& bucket, int& tok, float& wt) {
    const float c1 = (float)(319.0 / 20.0 + 1e-4);   // W/PW + B
    const float c2 = (float)(239.0 / 15.0 + 1e-4);   // H/PH + B
    const int pos = (int)(floorf(e.y / c1) + floorf(e.z / c2) * 20.0f);
    tok = (int)(floorf(fmodf(e.y, c1)) + floorf(fmodf(e.z, c2)) * 16.0f);
    const int dt = (int)floorf(4.0f * (e.x - t0) / d_dt);
    const int p  = (int)e.w;
    bucket = (dt * 2 + p) * 300 + pos;
    wt = (e.x - t0) / d_wt;
}

__global__ __launch_bounds__(TPB) void k_bin(const float4* __restrict__ x,
                                             uint32_t* __restrict__ payload,
                                             uint16_t* __restrict__ pfxT,
                                             int n) {
    __shared__ uint32_t stage[CHUNK];     // 16 KB
    __shared__ uint32_t cnt[NBUCKET];     // 9.6 KB: counts, then prefixes
    __shared__ uint32_t wsum[TPB / 64];   // 8 waves

    for (int i = threadIdx.x; i < NBUCKET; i += TPB) cnt[i] = 0;
    __syncthreads();

    const float* xf = (const float*)x;
    const float t0 = xf[0];
    const float tlast = xf[(size_t)(n - 1) * 4];
    const float d_wt = tlast - t0 + 1e-4f;
    const float d_dt = tlast - t0 + 1.0f;

    const int beg = blockIdx.x * CHUNK;
    const bool full = (beg + CHUNK <= n);

    // phase 1: classify once; atomicAdd returns within-bucket rank (stash it)
    uint32_t pk[EVT];
    uint32_t bk[EVT];
    if (full) {
        #pragma unroll
        for (int k = 0; k < EVT; ++k) {
            float4 e = x[beg + threadIdx.x + k * TPB];
            int bucket, tok; float wt;
            classify_full(e, t0, d_wt, d_dt, bucket, tok, wt);
            uint32_t q = (uint32_t)(wt * 1048576.0f);          // q20
            q = q > 1048575u ? 1048575u : q;
            pk[k] = ((uint32_t)tok << 24) | ((uint32_t)(bucket & 15) << 20) | q;
            uint32_t rank = atomicAdd(&cnt[bucket], 1u);
            bk[k] = (uint32_t)bucket | (rank << 12);           // bucket:12 rank:12
        }
    } else {
        #pragma unroll
        for (int k = 0; k < EVT; ++k) {
            const int i = beg + threadIdx.x + k * TPB;
            if (i < n) {
                float4 e = x[i];
                int bucket, tok; float wt;
                classify_full(e, t0, d_wt, d_dt, bucket, tok, wt);
                uint32_t q = (uint32_t)(wt * 1048576.0f);
                q = q > 1048575u ? 1048575u : q;
                pk[k] = ((uint32_t)tok << 24) | ((uint32_t)(bucket & 15) << 20) | q;
                uint32_t rank = atomicAdd(&cnt[bucket], 1u);
                bk[k] = (uint32_t)bucket | (rank << 12);
            } else {
                bk[k] = 0xFFFFFFFFu;
            }
        }
    }
    __syncthreads();

    // phase 2: block-local exclusive scan of NBUCKET counts
    uint32_t v[SCAN_PER];
    uint32_t sum = 0;
    const int base_i = threadIdx.x * SCAN_PER;
    #pragma unroll
    for (int j = 0; j < SCAN_PER; ++j) {
        int idx = base_i + j;
        uint32_t c = (idx < NBUCKET) ? cnt[idx] : 0u;
        v[j] = sum;
        sum += c;
    }
    uint32_t inc = sum;
    #pragma unroll
    for (int off = 1; off < 64; off <<= 1) {
        uint32_t u = __shfl_up(inc, off, 64);
        if ((threadIdx.x & 63) >= off) inc += u;
    }
    const int wid = threadIdx.x >> 6, lid = threadIdx.x & 63;
    if (lid == 63) wsum[wid] = inc;
    __syncthreads();
    uint32_t woff = 0;
    for (int w = 0; w < wid; ++w) woff += wsum[w];
    const uint32_t excl = woff + inc - sum;

    #pragma unroll
    for (int j = 0; j < SCAN_PER; ++j) {
        int idx = base_i + j;
        if (idx < NBUCKET) {
            uint32_t p = excl + v[j];
            cnt[idx] = p;                        // exclusive prefix (read-only below)
            if ((idx & 15) == 0)                 // group start, direct-transposed
                pfxT[(size_t)(idx >> 4) * B1 + blockIdx.x] = (uint16_t)p;
        }
    }
    __syncthreads();

    // phase 3: plain indexed store (rank came from the phase-1 atomic)
    if (full) {
        #pragma unroll
        for (int k = 0; k < EVT; ++k)
            stage[cnt[bk[k] & 0xFFFu] + (bk[k] >> 12)] = pk[k];
    } else {
        #pragma unroll
        for (int k = 0; k < EVT; ++k)
            if (bk[k] != 0xFFFFFFFFu)
                stage[cnt[bk[k] & 0xFFFu] + (bk[k] >> 12)] = pk[k];
    }
    __syncthreads();

    // phase 4: coalesced LDS -> global writeout
    const int end = min(beg + CHUNK, n);
    const int cntE = end > beg ? end - beg : 0;
    uint32_t* pbase = payload + (size_t)blockIdx.x * CHUNK;
    const int n4 = cntE >> 2;
    const uint4* s4 = (const uint4*)stage;
    uint4* g4 = (uint4*)pbase;
    for (int i = threadIdx.x; i < n4; i += TPB) g4[i] = s4[i];
    for (int i = (n4 << 2) + threadIdx.x; i < cntE; i += TPB) pbase[i] = stage[i];
}

// One block per (group, row-slice): 150 x 8 = 1200 blocks, 32 KB LDS hist
// -> 4 blocks/CU, 32 waves/CU. g = bid>>3, s = bid&7 so XCD s (round-robin
// bid%8) owns slice s of ALL groups: adjacent groups' shared boundary lines
// stay in one XCD L2. Each wave owns 64 rows; 16-lane quarters stream each
// row's payload span (coalesced u32 runs).
__global__ __launch_bounds__(ATPB) void k_accum(const uint32_t* __restrict__ payload,
                                                const uint16_t* __restrict__ pfxT,
                                                unsigned long long* __restrict__ partial,
                                                int n) {
    const int g = blockIdx.x >> 3;
    const int s = blockIdx.x & 7;

    __shared__ unsigned long long hist[HCELLS];   // 32 KB: (tok*16+c) -> cnt<<40 | q20sum
    for (int i = threadIdx.x; i < HCELLS; i += ATPB) hist[i] = 0ULL;
    __syncthreads();

    const uint16_t* colb = pfxT + (size_t)g * B1;
    const bool last = (g == NG - 1);
    const uint16_t* cole = colb + B1;             // valid iff !last

    const int wid = threadIdx.x >> 6, lid = threadIdx.x & 63;
    const int r0 = s * RPS + wid * 64;            // 8 waves x 64 rows = 512 = RPS

    const int row = r0 + lid;
    uint32_t vb = colb[row];                      // coalesced u16 loads
    uint32_t ve;
    if (!last) {
        ve = cole[row];
    } else {
        int rc = n - row * CHUNK;
        ve = rc < 0 ? 0 : (rc > CHUNK ? CHUNK : rc);
    }

    const int q4 = lid >> 4;                      // quarter 0..3
    const int ql = lid & 15;
    for (int r = 0; r < 64; r += 4) {
        const int rr = r + q4;
        const uint32_t sb = __shfl(vb, rr, 64);
        const uint32_t se = __shfl(ve, rr, 64);
        const uint32_t* seg = payload + (size_t)(r0 + rr) * CHUNK;
        for (uint32_t j = sb + ql; j < se; j += 16) {
            const uint32_t w = seg[j];
            atomicAdd(&hist[w >> 20],
                      (1ULL << 40) | (unsigned long long)(w & 0xFFFFFu));
        }
    }
    __syncthreads();

    // coalesced partial writeout (every cell written -> no ws pre-zero)
    unsigned long long* pp = partial + ((size_t)s * NG + g) * HCELLS;
    for (int i = threadIdx.x; i < HCELLS; i += ATPB) pp[i] = hist[i];
}

// Sum 8 partials per cell; coalesced reads AND writes (consecutive cells ->
// consecutive pos because key = tok*16 + c). 614,400 cells, each out written
// exactly once -> no out memset.
__global__ __launch_bounds__(256) void k_out(const unsigned long long* __restrict__ partial,
                                             float* __restrict__ out) {
    const int i = blockIdx.x * 256 + threadIdx.x;   // cell id
    unsigned long long v = 0ULL;
    #pragma unroll
    for (int s = 0; s < SLICES; ++s)
        v += partial[(size_t)s * (NG * HCELLS) + i];
    const int g = i >> 12;
    const int idx = i & 4095;
    const int tok = idx >> 4;
    const int c = idx & 15;
    const int b = g * GACC + c;
    const int pos = b % 300;
    const int dp = b / 300;
    const float cntf = (float)(uint32_t)(v >> 40);
    const float wts  = (float)(v & ((1ULL << 40) - 1)) * (1.0f / 1048576.0f);
    const int base0 = dp * OUT_DP_STRIDE + tok * 300 + pos;
    out[base0] = cntf;                     // channel 0: count
    out[base0 + OUT_CH_STRIDE] = wts;      // channel 1: wt sum
}

// ---- fallback (ws too small / n out of range) ----
__global__ __launch_bounds__(256) void e2src_hist_atomic(const float4* __restrict__ x,
                                                         float* __restrict__ out, int n) {
    const float* xf = (const float*)x;
    const float t0 = xf[0];
    const float tlast = xf[(size_t)(n - 1) * 4];
    const float d_wt = tlast - t0 + 1e-4f;
    const float d_dt = tlast - t0 + 1.0f;
    int i = blockIdx.x * blockDim.x + threadIdx.x;
    const int stride = gridDim.x * blockDim.x;
    for (; i < n; i += stride) {
        float4 e = x[i];
        int bucket, tok; float wt;
        classify_full(e, t0, d_wt, d_dt, bucket, tok, wt);
        const int dp = bucket / 300, pos = bucket % 300;
        const int base = dp * OUT_DP_STRIDE + tok * 300 + pos;
        unsafeAtomicAdd(out + base, 1.0f);
        unsafeAtomicAdd(out + base + OUT_CH_STRIDE, wt);
    }
}

extern "C" void kernel_launch(void* const* d_in, const int* in_sizes, int n_in,
                              void* d_out, int out_size, void* d_ws, size_t ws_size,
                              hipStream_t stream) {
    const float* x = (const float*)d_in[0];
    float* out = (float*)d_out;
    const int n = in_sizes[0] / 4;

    const size_t payload_bytes = ((size_t)n * 4u + 7u) & ~(size_t)7u;
    const size_t pfx_bytes = (size_t)B1 * NG * 2u;                 // 1,228,800
    const size_t part_bytes = (size_t)SLICES * NG * HCELLS * 8u;   // 39,321,600
    const size_t need = payload_bytes + pfx_bytes + part_bytes;

    if (ws_size < need || n > B1 * CHUNK || n <= 0) {
        hipMemsetAsync(d_out, 0, (size_t)out_size * sizeof(float), stream);
        if (n > 0)
            hipLaunchKernelGGL(e2src_hist_atomic, dim3(8192), dim3(256), 0, stream,
                               (const float4*)x, out, n);
        return;
    }

    uint32_t* payload = (uint32_t*)d_ws;
    uint16_t* pfxT = (uint16_t*)((char*)d_ws + payload_bytes);
    unsigned long long* partial =
        (unsigned long long*)((char*)d_ws + payload_bytes + pfx_bytes);

    hipLaunchKernelGGL(k_bin, dim3(B1), dim3(TPB), 0, stream,
                       (const float4*)x, payload, pfxT, n);
    hipLaunchKernelGGL(k_accum, dim3(NG * SLICES), dim3(ATPB), 0, stream,
                       payload, pfxT, partial, n);
    hipLaunchKernelGGL(k_out, dim3((NG * HCELLS) / 256), dim3(256), 0, stream,
                       partial, out);
}

// Round 5
// 447.377 us; speedup vs baseline: 1.0120x; 1.0038x over previous
//
#include <hip/hip_runtime.h>
#include <stdint.h>

// Round 12: fix k_accum LOAD IMBALANCE (the invariant that made r9/r10/r11
// all land at ~285us kernel-sum despite big traffic changes).
//  t is SORTED -> dt is a step function of row index -> group g's events
//  live only in the 1/4 of rows whose dt matches. With CONTIGUOUS slice
//  ranges, only 2 of 8 slices per group had any work: ~300 busy blocks
//  doing 4x average work = same makespan as round 7's 300-block kernel.
//  Fix: STRIDED slice mapping row = slocal*SLICES + s -> every slice
//  samples all dt uniformly -> all blocks ~7K events. SLICES 8->16
//  (2400 blocks, ~2.3 residency rounds at 4 blocks/CU). Mapping
//  g=bid>>4, s=bid&15 keeps (g,s)/(g+1,s) boundary lines on one XCD
//  (bids differ by 16 = 0 mod 8).
//  k_bin unchanged from r11 (TPB=512, EVT=8, spill-free).
//
// payload word: tok<<24 | (bucket&15)<<20 | q20(wt).  hist key = w>>20.
// ws: payload u32*n | pfxT u16[NG][B1] | partial u64[SLICES][NG][4096]

#define TPB 512
#define B1 4096
#define CHUNK 4096                 // B1*CHUNK = 2^24 = n
#define EVT (CHUNK / TPB)          // 8 events per thread (spill-free stash)
#define NBUCKET 2400
#define SCAN_PER 5                 // ceil(NBUCKET/TPB)
#define GACC 16                    // buckets per group
#define NG (NBUCKET / GACC)        // 150 groups
#define SLICES 16
#define RPS (B1 / SLICES)          // 256 slocal rows per slice
#define HCELLS (GACC * 256)        // 4096 cells per group
#define ATPB 512                   // k_accum block size (8 waves)
#define OUT_CH_STRIDE 76800        // 256*300
#define OUT_DP_STRIDE 153600       // 2*256*300

__device__ __forceinline__ void classify_full(const float4 e, const float t0,
                                              const float d_wt, const float d_dt,
                                              int& bucket, int& tok, float& wt) {
    const float c1 = (float)(319.0 / 20.0 + 1e-4);   // W/PW + B
    const float c2 = (float)(239.0 / 15.0 + 1e-4);   // H/PH + B
    const int pos = (int)(floorf(e.y / c1) + floorf(e.z / c2) * 20.0f);
    tok = (int)(floorf(fmodf(e.y, c1)) + floorf(fmodf(e.z, c2)) * 16.0f);
    const int dt = (int)floorf(4.0f * (e.x - t0) / d_dt);
    const int p  = (int)e.w;
    bucket = (dt * 2 + p) * 300 + pos;
    wt = (e.x - t0) / d_wt;
}

__global__ __launch_bounds__(TPB) void k_bin(const float4* __restrict__ x,
                                             uint32_t* __restrict__ payload,
                                             uint16_t* __restrict__ pfxT,
                                             int n) {
    __shared__ uint32_t stage[CHUNK];     // 16 KB
    __shared__ uint32_t cnt[NBUCKET];     // 9.6 KB: counts, then prefixes
    __shared__ uint32_t wsum[TPB / 64];   // 8 waves

    for (int i = threadIdx.x; i < NBUCKET; i += TPB) cnt[i] = 0;
    __syncthreads();

    const float* xf = (const float*)x;
    const float t0 = xf[0];
    const float tlast = xf[(size_t)(n - 1) * 4];
    const float d_wt = tlast - t0 + 1e-4f;
    const float d_dt = tlast - t0 + 1.0f;

    const int beg = blockIdx.x * CHUNK;
    const bool full = (beg + CHUNK <= n);

    // phase 1: classify once; atomicAdd returns within-bucket rank (stash it)
    uint32_t pk[EVT];
    uint32_t bk[EVT];
    if (full) {
        #pragma unroll
        for (int k = 0; k < EVT; ++k) {
            float4 e = x[beg + threadIdx.x + k * TPB];
            int bucket, tok; float wt;
            classify_full(e, t0, d_wt, d_dt, bucket, tok, wt);
            uint32_t q = (uint32_t)(wt * 1048576.0f);          // q20
            q = q > 1048575u ? 1048575u : q;
            pk[k] = ((uint32_t)tok << 24) | ((uint32_t)(bucket & 15) << 20) | q;
            uint32_t rank = atomicAdd(&cnt[bucket], 1u);
            bk[k] = (uint32_t)bucket | (rank << 12);           // bucket:12 rank:12
        }
    } else {
        #pragma unroll
        for (int k = 0; k < EVT; ++k) {
            const int i = beg + threadIdx.x + k * TPB;
            if (i < n) {
                float4 e = x[i];
                int bucket, tok; float wt;
                classify_full(e, t0, d_wt, d_dt, bucket, tok, wt);
                uint32_t q = (uint32_t)(wt * 1048576.0f);
                q = q > 1048575u ? 1048575u : q;
                pk[k] = ((uint32_t)tok << 24) | ((uint32_t)(bucket & 15) << 20) | q;
                uint32_t rank = atomicAdd(&cnt[bucket], 1u);
                bk[k] = (uint32_t)bucket | (rank << 12);
            } else {
                bk[k] = 0xFFFFFFFFu;
            }
        }
    }
    __syncthreads();

    // phase 2: block-local exclusive scan of NBUCKET counts
    uint32_t v[SCAN_PER];
    uint32_t sum = 0;
    const int base_i = threadIdx.x * SCAN_PER;
    #pragma unroll
    for (int j = 0; j < SCAN_PER; ++j) {
        int idx = base_i + j;
        uint32_t c = (idx < NBUCKET) ? cnt[idx] : 0u;
        v[j] = sum;
        sum += c;
    }
    uint32_t inc = sum;
    #pragma unroll
    for (int off = 1; off < 64; off <<= 1) {
        uint32_t u = __shfl_up(inc, off, 64);
        if ((threadIdx.x & 63) >= off) inc += u;
    }
    const int wid = threadIdx.x >> 6, lid = threadIdx.x & 63;
    if (lid == 63) wsum[wid] = inc;
    __syncthreads();
    uint32_t woff = 0;
    for (int w = 0; w < wid; ++w) woff += wsum[w];
    const uint32_t excl = woff + inc - sum;

    #pragma unroll
    for (int j = 0; j < SCAN_PER; ++j) {
        int idx = base_i + j;
        if (idx < NBUCKET) {
            uint32_t p = excl + v[j];
            cnt[idx] = p;                        // exclusive prefix (read-only below)
            if ((idx & 15) == 0)                 // group start, direct-transposed
                pfxT[(size_t)(idx >> 4) * B1 + blockIdx.x] = (uint16_t)p;
        }
    }
    __syncthreads();

    // phase 3: plain indexed store (rank came from the phase-1 atomic)
    if (full) {
        #pragma unroll
        for (int k = 0; k < EVT; ++k)
            stage[cnt[bk[k] & 0xFFFu] + (bk[k] >> 12)] = pk[k];
    } else {
        #pragma unroll
        for (int k = 0; k < EVT; ++k)
            if (bk[k] != 0xFFFFFFFFu)
                stage[cnt[bk[k] & 0xFFFu] + (bk[k] >> 12)] = pk[k];
    }
    __syncthreads();

    // phase 4: coalesced LDS -> global writeout
    const int end = min(beg + CHUNK, n);
    const int cntE = end > beg ? end - beg : 0;
    uint32_t* pbase = payload + (size_t)blockIdx.x * CHUNK;
    const int n4 = cntE >> 2;
    const uint4* s4 = (const uint4*)stage;
    uint4* g4 = (uint4*)pbase;
    for (int i = threadIdx.x; i < n4; i += TPB) g4[i] = s4[i];
    for (int i = (n4 << 2) + threadIdx.x; i < cntE; i += TPB) pbase[i] = stage[i];
}

// One block per (group, slice): 150 x 16 = 2400 blocks. STRIDED rows:
// slice s owns rows {slocal*16 + s}, so every slice samples all dt ranges
// -> balanced ~7K events/block (t-sorted input makes contiguous ranges
// 4x imbalanced). 32 KB LDS hist -> 4 blocks/CU. g=bid>>4, s=bid&15 keeps
// (g,s)/(g+1,s) shared boundary lines on one XCD. 8 waves x 32 rows each;
// 16-lane quarters stream each row's payload span.
__global__ __launch_bounds__(ATPB) void k_accum(const uint32_t* __restrict__ payload,
                                                const uint16_t* __restrict__ pfxT,
                                                unsigned long long* __restrict__ partial,
                                                int n) {
    const int g = blockIdx.x >> 4;
    const int s = blockIdx.x & 15;

    __shared__ unsigned long long hist[HCELLS];   // 32 KB: (tok*16+c) -> cnt<<40 | q20sum
    for (int i = threadIdx.x; i < HCELLS; i += ATPB) hist[i] = 0ULL;
    __syncthreads();

    const uint16_t* colb = pfxT + (size_t)g * B1;
    const bool last = (g == NG - 1);
    const uint16_t* cole = colb + B1;             // valid iff !last

    const int wid = threadIdx.x >> 6, lid = threadIdx.x & 63;
    const int s0 = wid * (RPS / 8);               // 8 waves x 32 slocal rows

    // lanes 0..31 hold the wave's 32 row offsets (strided rows)
    uint32_t vb = 0, ve = 0;
    if (lid < RPS / 8) {
        const int row = (s0 + lid) * SLICES + s;
        vb = colb[row];
        if (!last) {
            ve = cole[row];
        } else {
            int rc = n - row * CHUNK;
            ve = rc < 0 ? 0 : (rc > CHUNK ? CHUNK : rc);
        }
    }

    const int q4 = lid >> 4;                      // quarter 0..3
    const int ql = lid & 15;
    for (int r = 0; r < RPS / 8; r += 4) {
        const int rr = r + q4;                    // 0..31
        const uint32_t sb = __shfl(vb, rr, 64);
        const uint32_t se = __shfl(ve, rr, 64);
        const uint32_t* seg = payload + (size_t)((s0 + rr) * SLICES + s) * CHUNK;
        for (uint32_t j = sb + ql; j < se; j += 16) {
            const uint32_t w = seg[j];
            atomicAdd(&hist[w >> 20],
                      (1ULL << 40) | (unsigned long long)(w & 0xFFFFFu));
        }
    }
    __syncthreads();

    // coalesced partial writeout (every cell written -> no ws pre-zero)
    unsigned long long* pp = partial + ((size_t)s * NG + g) * HCELLS;
    for (int i = threadIdx.x; i < HCELLS; i += ATPB) pp[i] = hist[i];
}

// Sum 16 partials per cell; coalesced reads AND writes (consecutive cells ->
// consecutive pos because key = tok*16 + c). 614,400 cells, each out written
// exactly once -> no out memset.
__global__ __launch_bounds__(256) void k_out(const unsigned long long* __restrict__ partial,
                                             float* __restrict__ out) {
    const int i = blockIdx.x * 256 + threadIdx.x;   // cell id
    unsigned long long v = 0ULL;
    #pragma unroll
    for (int s = 0; s < SLICES; ++s)
        v += partial[(size_t)s * (NG * HCELLS) + i];
    const int g = i >> 12;
    const int idx = i & 4095;
    const int tok = idx >> 4;
    const int c = idx & 15;
    const int b = g * GACC + c;
    const int pos = b % 300;
    const int dp = b / 300;
    const float cntf = (float)(uint32_t)(v >> 40);
    const float wts  = (float)(v & ((1ULL << 40) - 1)) * (1.0f / 1048576.0f);
    const int base0 = dp * OUT_DP_STRIDE + tok * 300 + pos;
    out[base0] = cntf;                     // channel 0: count
    out[base0 + OUT_CH_STRIDE] = wts;      // channel 1: wt sum
}

// ---- fallback (ws too small / n out of range) ----
__global__ __launch_bounds__(256) void e2src_hist_atomic(const float4* __restrict__ x,
                                                         float* __restrict__ out, int n) {
    const float* xf = (const float*)x;
    const float t0 = xf[0];
    const float tlast = xf[(size_t)(n - 1) * 4];
    const float d_wt = tlast - t0 + 1e-4f;
    const float d_dt = tlast - t0 + 1.0f;
    int i = blockIdx.x * blockDim.x + threadIdx.x;
    const int stride = gridDim.x * blockDim.x;
    for (; i < n; i += stride) {
        float4 e = x[i];
        int bucket, tok; float wt;
        classify_full(e, t0, d_wt, d_dt, bucket, tok, wt);
        const int dp = bucket / 300, pos = bucket % 300;
        const int base = dp * OUT_DP_STRIDE + tok * 300 + pos;
        unsafeAtomicAdd(out + base, 1.0f);
        unsafeAtomicAdd(out + base + OUT_CH_STRIDE, wt);
    }
}

extern "C" void kernel_launch(void* const* d_in, const int* in_sizes, int n_in,
                              void* d_out, int out_size, void* d_ws, size_t ws_size,
                              hipStream_t stream) {
    const float* x = (const float*)d_in[0];
    float* out = (float*)d_out;
    const int n = in_sizes[0] / 4;

    const size_t payload_bytes = ((size_t)n * 4u + 7u) & ~(size_t)7u;
    const size_t pfx_bytes = (size_t)B1 * NG * 2u;                 // 1,228,800
    const size_t part_bytes = (size_t)SLICES * NG * HCELLS * 8u;   // 78,643,200
    const size_t need = payload_bytes + pfx_bytes + part_bytes;

    if (ws_size < need || n > B1 * CHUNK || n <= 0) {
        hipMemsetAsync(d_out, 0, (size_t)out_size * sizeof(float), stream);
        if (n > 0)
            hipLaunchKernelGGL(e2src_hist_atomic, dim3(8192), dim3(256), 0, stream,
                               (const float4*)x, out, n);
        return;
    }

    uint32_t* payload = (uint32_t*)d_ws;
    uint16_t* pfxT = (uint16_t*)((char*)d_ws + payload_bytes);
    unsigned long long* partial =
        (unsigned long long*)((char*)d_ws + payload_bytes + pfx_bytes);

    hipLaunchKernelGGL(k_bin, dim3(B1), dim3(TPB), 0, stream,
                       (const float4*)x, payload, pfxT, n);
    hipLaunchKernelGGL(k_accum, dim3(NG * SLICES), dim3(ATPB), 0, stream,
                       payload, pfxT, partial, n);
    hipLaunchKernelGGL(k_out, dim3((NG * HCELLS) / 256), dim3(256), 0, stream,
                       partial, out);
}